// Round 19
// baseline (95.773 us; speedup 1.0000x reference)
//
#include <hip/hip_runtime.h>
#include <hip/hip_bf16.h>

#define S_LEN 2048
#define E_DIM 1024
#define NH 16
#define HD 64
#define ATTN_SCALE 0.03125f                 // 1/sqrt(1024)
#define QSCALE_L2E 0.045084312f             // ATTN_SCALE * log2(e): exp2-domain softmax
#define KVB 128

typedef __attribute__((ext_vector_type(8))) short short8;
typedef __attribute__((ext_vector_type(8))) unsigned short ushort8;
typedef __attribute__((ext_vector_type(4))) unsigned short ushort4_t;
typedef __attribute__((ext_vector_type(4))) float f32x4;
typedef __attribute__((ext_vector_type(4))) float f4;
typedef __attribute__((ext_vector_type(2))) unsigned int uint2_t;

__device__ __forceinline__ float bf2f(unsigned short u) {
    unsigned int x = ((unsigned int)u) << 16;
    return __builtin_bit_cast(float, x);
}
__device__ __forceinline__ unsigned short f2bf(float f) {
    unsigned int x = __builtin_bit_cast(unsigned int, f);
    x += 0x7FFFu + ((x >> 16) & 1u);   // RNE
    return (unsigned short)(x >> 16);
}
__device__ __forceinline__ float exp2_fast(float x) {   // 2^x, one v_exp_f32
    float r;
    asm("v_exp_f32 %0, %1" : "=v"(r) : "v"(x));
    return r;
}
__device__ __forceinline__ void gload16(const unsigned short* g, unsigned short* l) {
    __builtin_amdgcn_global_load_lds(
        (__attribute__((address_space(1))) void*)g,
        (__attribute__((address_space(3))) void*)l, 16, 0, 0);
}

// ---------------- merged prep: x->bf16 | rope table | W transpose ----------------
__global__ __launch_bounds__(256) void k_prep(const float* __restrict__ x,
                                              unsigned short* __restrict__ xb,
                                              const float* W0, const float* W1,
                                              const float* W2, const float* W3,
                                              unsigned short* Tqkv,
                                              unsigned short* Twout,
                                              float* __restrict__ cosT,
                                              float* __restrict__ sinT) {
    int bid = blockIdx.x;
    int tid = threadIdx.x;
    if (bid < 2048) {
        size_t i = ((size_t)bid * 256 + tid) * 8;
        f4 a = *(const f4*)(x + i);
        f4 b = *(const f4*)(x + i + 4);
        ushort8 o;
        o[0] = f2bf(a[0]); o[1] = f2bf(a[1]); o[2] = f2bf(a[2]); o[3] = f2bf(a[3]);
        o[4] = f2bf(b[0]); o[5] = f2bf(b[1]); o[6] = f2bf(b[2]); o[7] = f2bf(b[3]);
        *(ushort8*)(xb + i) = o;
    } else if (bid < 2304) {
        int idx = (bid - 2048) * 256 + tid;
        int s = idx >> 5, j = idx & 31;
        float inv = expf(-(float)j * (9.210340371976184f / 32.f));
        float ang = (float)s * inv;
        cosT[idx] = cosf(ang);
        sinT[idx] = sinf(ang);
    } else {
        int t = bid - 2304;                  // 0..4095
        int bx = (t & 31) * 32, by = ((t >> 5) & 31) * 32, z = t >> 10;
        const float* W; unsigned short* T;
        switch (z) {
            case 0: W = W0; T = Tqkv; break;
            case 1: W = W1; T = Tqkv + 1048576; break;
            case 2: W = W2; T = Tqkv + 2097152; break;
            default: W = W3; T = Twout; break;
        }
        __shared__ float tile[32][33];
        int tx = tid & 31, ty = tid >> 5;    // 32 x 8
#pragma unroll
        for (int i = 0; i < 4; i++)
            tile[ty + i * 8][tx] = W[(size_t)(by + ty + i * 8) * E_DIM + bx + tx];
        __syncthreads();
#pragma unroll
        for (int i = 0; i < 4; i++)
            T[(size_t)(bx + ty + i * 8) * E_DIM + by + tx] = f2bf(tile[tx][ty + i * 8]);
    }
}

// ---------------- QKV GEMM, m97 structure with BK=64 (R18, unchanged) -----------
__global__ __launch_bounds__(256, 3)
void k_gemm97(const unsigned short* __restrict__ A,
              const unsigned short* __restrict__ B,
              unsigned short* __restrict__ Qo,
              unsigned short* __restrict__ Ko,
              unsigned short* __restrict__ Vto,
              const float* __restrict__ cosT,
              const float* __restrict__ sinT) {
    constexpr int NBN = 24;
    constexpr int NWG = 32 * NBN;            // 768
    __shared__ unsigned short Alds[128 * 64];
    __shared__ unsigned short Blds[128 * 64];
    int tid = threadIdx.x, lane = tid & 63, wid = tid >> 6;
    int l15 = lane & 15, lg = lane >> 4;
    int wr = wid >> 1, wc = wid & 1;
    int orig = blockIdx.y * NBN + blockIdx.x;
    int wg = (orig & 7) * (NWG / 8) + (orig >> 3);   // bijective XCD swizzle
    int bm = wg / NBN, bn = wg % NBN;

    f32x4 acc[4][4] = {};
    for (int k0 = 0; k0 < E_DIM; k0 += 64) {
#pragma unroll
        for (int i = 0; i < 4; i++) {        // A: 4 x 1KB segments per wave
            int r = wid * 32 + i * 8 + (lane >> 3);
            int cs = (lane & 7) ^ (r & 7);
            gload16(A + (size_t)(bm * 128 + r) * E_DIM + k0 + cs * 8,
                    Alds + (wid * 256 + i * 64) * 8);
        }
#pragma unroll
        for (int i = 0; i < 4; i++) {        // B: 4 x 1KB segments per wave
            int r = wid * 32 + i * 8 + (lane >> 3);
            int cs = (lane & 7) ^ (r & 7);
            gload16(B + (size_t)(bn * 128 + r) * E_DIM + k0 + cs * 8,
                    Blds + (wid * 256 + i * 64) * 8);
        }
        __syncthreads();
#pragma unroll
        for (int ks = 0; ks < 2; ks++) {
            short8 af[4], bfr[4];
#pragma unroll
            for (int mf = 0; mf < 4; mf++) {
                int r = wr * 64 + mf * 16 + l15;
                int gc = ks * 4 + lg;
                af[mf] = *(const short8*)(Alds + r * 64 + ((gc ^ (r & 7)) << 3));
            }
#pragma unroll
            for (int nf = 0; nf < 4; nf++) {
                int r = wc * 64 + nf * 16 + l15;
                int gc = ks * 4 + lg;
                bfr[nf] = *(const short8*)(Blds + r * 64 + ((gc ^ (r & 7)) << 3));
            }
            __builtin_amdgcn_s_setprio(1);
#pragma unroll
            for (int mf = 0; mf < 4; mf++)
#pragma unroll
                for (int nf = 0; nf < 4; nf++)
                    acc[mf][nf] = __builtin_amdgcn_mfma_f32_16x16x32_bf16(
                        af[mf], bfr[nf], acc[mf][nf], 0, 0, 0);
            __builtin_amdgcn_s_setprio(0);
        }
        __syncthreads();
    }
    // epilogue: fused RoPE for Q/K, Vt[bh][d][s] scatter for V
#pragma unroll
    for (int mf = 0; mf < 4; mf++) {
        int r0 = bm * 128 + wr * 64 + mf * 16 + lg * 4;
#pragma unroll
        for (int nf = 0; nf < 4; nf++) {
            int colg = bn * 128 + wc * 64 + nf * 16 + l15;
            int z = colg >> 10, c1 = colg & 1023;
            if (z == 2) {
                int h = c1 >> 6, d = c1 & 63;
                int bb = r0 >> 11, s = r0 & 2047;
                ushort4_t p;
#pragma unroll
                for (int r = 0; r < 4; r++) p[r] = f2bf(acc[mf][nf][r]);
                *(ushort4_t*)(Vto + (((size_t)((bb * 16 + h) * 64 + d)) << 11) + s) = p;
            } else {
                unsigned short* T = z ? Ko : Qo;
                int dl = c1 & 63, j = dl >> 1;
                float sgn = (dl & 1) ? 1.f : -1.f;
                float scq = z ? 1.f : QSCALE_L2E;
#pragma unroll
                for (int r = 0; r < 4; r++) {
                    int row = r0 + r, s = row & 2047;
                    float c = cosT[s * 32 + j], sn = sinT[s * 32 + j];
                    float v = acc[mf][nf][r];
                    float p = __shfl_xor(v, 1);
                    T[(size_t)row * E_DIM + c1] = f2bf((v * c + sgn * p * sn) * scq);
                }
            }
        }
    }
}

// ---------------- out-proj GEMM: same m97/BK=64 structure, 128x64 tile ----------
// C[4096][1024] f32 = AO * WoT^T. 4 waves (2x2), per-wave 64x32 out, 16 K-steps.
// LDS 24KB -> 3 blocks/CU capable; grid 512 (2/CU).
__global__ __launch_bounds__(256, 3)
void k_gemmo97(const unsigned short* __restrict__ A,
               const unsigned short* __restrict__ B,
               float* __restrict__ Fo) {
    constexpr int NBN = 16;                  // 1024/64
    constexpr int NWG = 32 * NBN;            // 512
    __shared__ unsigned short Alds[128 * 64];
    __shared__ unsigned short Blds[64 * 64];
    int tid = threadIdx.x, lane = tid & 63, wid = tid >> 6;
    int l15 = lane & 15, lg = lane >> 4;
    int wr = wid >> 1, wc = wid & 1;
    int orig = blockIdx.y * NBN + blockIdx.x;
    int wg = (orig & 7) * (NWG / 8) + (orig >> 3);   // bijective XCD swizzle
    int bm = wg / NBN, bn = wg % NBN;

    f32x4 acc[4][2] = {};
    for (int k0 = 0; k0 < E_DIM; k0 += 64) {
#pragma unroll
        for (int i = 0; i < 4; i++) {        // A: 4 x 1KB segments per wave
            int r = wid * 32 + i * 8 + (lane >> 3);
            int cs = (lane & 7) ^ (r & 7);
            gload16(A + (size_t)(bm * 128 + r) * E_DIM + k0 + cs * 8,
                    Alds + (wid * 256 + i * 64) * 8);
        }
        {                                    // B: 2 x 1KB segments per wave
#pragma unroll
            for (int i = 0; i < 2; i++) {
                int r = wid * 16 + i * 8 + (lane >> 3);
                int cs = (lane & 7) ^ (r & 7);
                gload16(B + (size_t)(bn * 64 + r) * E_DIM + k0 + cs * 8,
                        Blds + (wid * 128 + i * 64) * 8);
            }
        }
        __syncthreads();
#pragma unroll
        for (int ks = 0; ks < 2; ks++) {
            short8 af[4], bfr[2];
#pragma unroll
            for (int mf = 0; mf < 4; mf++) {
                int r = wr * 64 + mf * 16 + l15;
                int gc = ks * 4 + lg;
                af[mf] = *(const short8*)(Alds + r * 64 + ((gc ^ (r & 7)) << 3));
            }
#pragma unroll
            for (int nf = 0; nf < 2; nf++) {
                int r = wc * 32 + nf * 16 + l15;
                int gc = ks * 4 + lg;
                bfr[nf] = *(const short8*)(Blds + r * 64 + ((gc ^ (r & 7)) << 3));
            }
            __builtin_amdgcn_s_setprio(1);
#pragma unroll
            for (int mf = 0; mf < 4; mf++)
#pragma unroll
                for (int nf = 0; nf < 2; nf++)
                    acc[mf][nf] = __builtin_amdgcn_mfma_f32_16x16x32_bf16(
                        af[mf], bfr[nf], acc[mf][nf], 0, 0, 0);
            __builtin_amdgcn_s_setprio(0);
        }
        __syncthreads();
    }
#pragma unroll
    for (int mf = 0; mf < 4; mf++) {
        int r0 = bm * 128 + wr * 64 + mf * 16 + lg * 4;
#pragma unroll
        for (int nf = 0; nf < 2; nf++) {
            int colg = bn * 64 + wc * 32 + nf * 16 + l15;
#pragma unroll
            for (int r = 0; r < 4; r++)
                Fo[(size_t)(r0 + r) * E_DIM + colg] = acc[mf][nf][r];
        }
    }
}

// ---------------- causal flash attention (R18 + defer-max T13) ------------------
// 4 waves x 16 q-rows = one 64-row q-tile per block; 1024 blocks big-first;
// 4 bh per XCD. R11 4-barrier counted-vmcnt schedule, KVB=128, v_exp softmax
// (exp2 domain, log2e pre-folded into Q), cvt_pk P->bf16, defer-max THR=8.
__global__ __launch_bounds__(256, 3) void k_attn(const unsigned short* __restrict__ Q,
                                                 const unsigned short* __restrict__ K,
                                                 const unsigned short* __restrict__ Vt,
                                                 unsigned short* __restrict__ O) {
    __shared__ unsigned short K_lds[128 * 64];
    __shared__ unsigned short V_lds[64 * 128];
    __shared__ unsigned short P_lds[4][16][136];
    int tid = threadIdx.x, lane = tid & 63, wid = tid >> 6;
    int l15 = lane & 15, lg = lane >> 4;
    int orig = blockIdx.y * 32 + blockIdx.x;         // 1024 wgs
    int xcd = orig & 7, idx = orig >> 3;             // 128 per XCD
    int bh = xcd * 4 + (idx & 3);                    // 4 bh per XCD (L2 locality)
    int qt = 31 - ((idx >> 2) & 31);                 // big tiles first
    int b = bh >> 4, h = bh & 15;
    const size_t base_qk = (size_t)b * S_LEN * E_DIM + (size_t)h * HD;
    const unsigned short* Vbh = Vt + ((size_t)(bh * 64) << 11);

    auto stageK = [&](int kt) {
        const unsigned short* Kb = K + base_qk + (size_t)(kt * KVB) * E_DIM;
#pragma unroll
        for (int i = 0; i < 4; i++) {
            int r = i * 32 + wid * 8 + (lane >> 3);
            int cs = (lane & 7) ^ (r & 7);
            gload16(Kb + (size_t)r * E_DIM + cs * 8, K_lds + i * 2048 + wid * 512);
        }
    };
    auto stageV = [&](int kt) {
#pragma unroll
        for (int i = 0; i < 4; i++) {
            int r = i * 16 + wid * 4 + (lane >> 4);
            int cs = (lane & 15) ^ (r & 7);
            gload16(Vbh + (size_t)r * 2048 + kt * KVB + cs * 8,
                    V_lds + i * 2048 + wid * 512);
        }
    };

    const unsigned short* Qb = Q + base_qk + (size_t)(qt * 64 + wid * 16) * E_DIM;
    short8 bq[2];
#pragma unroll
    for (int s2 = 0; s2 < 2; s2++)
        bq[s2] = *(const short8*)(Qb + (size_t)l15 * E_DIM + s2 * 32 + lg * 8);
    f32x4 acc_o[4] = {};
    float m_i = -1e30f, l_i = 0.f;
    int q_glob = qt * 64 + wid * 16 + l15;
    int nkt = (qt + 2) >> 1;
    stageK(0);
    stageV(0);
    asm volatile("s_waitcnt vmcnt(4)" ::: "memory");   // own K0 done
    __builtin_amdgcn_s_barrier();                      // all waves' K0 landed
    __builtin_amdgcn_sched_barrier(0);
    for (int kt = 0; kt < nkt; ++kt) {
        // S^T = K . Q^T (exp2 domain; scale*log2e pre-folded into Q)
        f32x4 acc_s[8] = {};
        __builtin_amdgcn_s_setprio(1);
#pragma unroll
        for (int mf = 0; mf < 8; mf++) {
            int rK = mf * 16 + l15;
#pragma unroll
            for (int s2 = 0; s2 < 2; s2++) {
                int gc = s2 * 4 + lg;
                short8 a = *(const short8*)&K_lds[rK * 64 + ((gc ^ (rK & 7)) << 3)];
                acc_s[mf] = __builtin_amdgcn_mfma_f32_16x16x32_bf16(
                    a, bq[s2], acc_s[mf], 0, 0, 0);
            }
        }
        __builtin_amdgcn_s_setprio(0);
        __builtin_amdgcn_s_barrier();       // B1: K_lds free
        if (kt + 1 < nkt) stageK(kt + 1);
        float sv[32];
        float vmax = -1e30f;
        if (kt == nkt - 1) {
#pragma unroll
            for (int mf = 0; mf < 8; mf++)
#pragma unroll
                for (int r = 0; r < 4; r++) {
                    int kg = kt * KVB + mf * 16 + lg * 4 + r;
                    float v = acc_s[mf][r];
                    if (kg > q_glob) v = -1e30f;
                    sv[mf * 4 + r] = v;
                    vmax = fmaxf(vmax, v);
                }
        } else {
#pragma unroll
            for (int mf = 0; mf < 8; mf++)
#pragma unroll
                for (int r = 0; r < 4; r++) {
                    float v = acc_s[mf][r];
                    sv[mf * 4 + r] = v;
                    vmax = fmaxf(vmax, v);
                }
        }
        vmax = fmaxf(vmax, __shfl_xor(vmax, 16));
        vmax = fmaxf(vmax, __shfl_xor(vmax, 32));
        // defer-max (T13): rescale only when tile max grew by > 8 (exp2 domain)
        if (!__all(vmax - m_i <= 8.0f)) {
            float m_new = fmaxf(m_i, vmax);
            float corr = exp2_fast(m_i - m_new);
            l_i *= corr;
#pragma unroll
            for (int r = 0; r < 4; r++) {
                float c4 = __shfl(corr, lg * 4 + r);
#pragma unroll
                for (int nf = 0; nf < 4; nf++) acc_o[nf][r] *= c4;
            }
            m_i = m_new;
        }
        float rowsum = 0.f;
#pragma unroll
        for (int i = 0; i < 32; i++) {
            float p = exp2_fast(sv[i] - m_i);
            sv[i] = p;
            rowsum += p;
        }
        rowsum += __shfl_xor(rowsum, 16);
        rowsum += __shfl_xor(rowsum, 32);
        l_i += rowsum;
        // P -> bf16 via cvt_pk, wave-private LDS [q][k]
#pragma unroll
        for (int mf = 0; mf < 8; mf++) {
            unsigned int w0, w1;
            asm("v_cvt_pk_bf16_f32 %0, %1, %2"
                : "=v"(w0) : "v"(sv[mf * 4 + 0]), "v"(sv[mf * 4 + 1]));
            asm("v_cvt_pk_bf16_f32 %0, %1, %2"
                : "=v"(w1) : "v"(sv[mf * 4 + 2]), "v"(sv[mf * 4 + 3]));
            uint2_t w; w[0] = w0; w[1] = w1;
            *(uint2_t*)&P_lds[wid][l15][mf * 16 + lg * 4] = w;
        }
        if (kt + 1 < nkt)
            asm volatile("s_waitcnt vmcnt(4)" ::: "memory");  // own V(kt) done
        else
            asm volatile("s_waitcnt vmcnt(0)" ::: "memory");
        __builtin_amdgcn_s_barrier();       // B2: all V(kt) landed
        __builtin_amdgcn_sched_barrier(0);
        // PV: O += P . V
        __builtin_amdgcn_s_setprio(1);
#pragma unroll
        for (int s2 = 0; s2 < 4; s2++) {
            short8 pa = *(const short8*)&P_lds[wid][l15][s2 * 32 + lg * 8];
#pragma unroll
            for (int nf = 0; nf < 4; nf++) {
                int rV = nf * 16 + l15;
                int gc = s2 * 4 + lg;
                short8 bv = *(const short8*)&V_lds[rV * 128 + ((gc ^ (rV & 7)) << 3)];
                acc_o[nf] = __builtin_amdgcn_mfma_f32_16x16x32_bf16(
                    pa, bv, acc_o[nf], 0, 0, 0);
            }
        }
        __builtin_amdgcn_s_setprio(0);
        __builtin_amdgcn_s_barrier();       // B3: V_lds free
        if (kt + 1 < nkt) {
            stageV(kt + 1);
            asm volatile("s_waitcnt vmcnt(4)" ::: "memory");  // own K(kt+1) done
        }
        __builtin_amdgcn_s_barrier();       // B4: all K(kt+1) landed
        __builtin_amdgcn_sched_barrier(0);
    }
    unsigned short* Ob = O + base_qk + (size_t)(qt * 64 + wid * 16) * E_DIM;
#pragma unroll
    for (int r = 0; r < 4; r++) {
        float linv = 1.f / __shfl(l_i, lg * 4 + r);
#pragma unroll
        for (int nf = 0; nf < 4; nf++)
            Ob[(size_t)(lg * 4 + r) * E_DIM + nf * 16 + l15] =
                f2bf(acc_o[nf][r] * linv);
    }
}

extern "C" void kernel_launch(void* const* d_in, const int* in_sizes, int n_in,
                              void* d_out, int out_size, void* d_ws, size_t ws_size,
                              hipStream_t stream) {
    (void)in_sizes; (void)n_in; (void)out_size; (void)ws_size;
    const float* x  = (const float*)d_in[0];
    const float* Wq = (const float*)d_in[1];
    const float* Wk = (const float*)d_in[2];
    const float* Wv = (const float*)d_in[3];
    const float* Wo = (const float*)d_in[4];

    unsigned short* us = (unsigned short*)d_ws;
    unsigned short* xb    = us;                  // 4096x1024
    unsigned short* WqkvT = us + 4194304;        // 3072x1024 (Wq;Wk;Wv rows)
    unsigned short* WoT   = us + 7340032;        // 1024x1024
    unsigned short* Qb    = us + 8388608;        // 4096x1024 (roped, *scale*log2e)
    unsigned short* Kb    = us + 12582912;       // 4096x1024 (roped)
    unsigned short* Vt    = us + 16777216;       // [b][h][d][s] = [2][16][64][2048]
    unsigned short* AO    = us + 20971520;
    float* cosT = (float*)((char*)d_ws + 50331648);
    float* sinT = cosT + 65536;

    k_prep<<<6400, 256, 0, stream>>>(x, xb, Wq, Wk, Wv, Wo, WqkvT, WoT, cosT, sinT);
    k_gemm97<<<dim3(24, 32), 256, 0, stream>>>(xb, WqkvT, Qb, Kb, Vt, cosT, sinT);
    k_attn<<<dim3(32, 32), 256, 0, stream>>>(Qb, Kb, Vt, AO);
    k_gemmo97<<<dim3(16, 32), 256, 0, stream>>>(AO, WoT, (float*)d_out);
}